// Round 4
// baseline (1809.508 us; speedup 1.0000x reference)
//
#include <hip/hip_runtime.h>
#include <hip/hip_bf16.h>

#define NPIX   65536
#define TT     5
#define CC     10
#define HH     32
#define WIDTH  64
#define KW     32
#define OUTC   10

// ---- workspace layout (float offsets) ----
#define OFF_PB0IF   0
#define OFF_PB0GO   64
#define OFF_PB1IF   128
#define OFF_PB1GO   192
#define OFF_PW0I_IF 256
#define OFF_PW0I_GO 896
#define OFF_PW0H_IF 1536
#define OFF_PW0H_GO 3584
#define OFF_PW1I_IF 5632
#define OFF_PW1I_GO 7680
#define OFF_PW1H_IF 9728
#define OFF_PW1H_GO 11776
#define OFF_FC1W    13824
#define OFF_FC1B    15872
#define OFF_CWT2    16384
#define OFF_CB      32768
#define OFF_FC2W2   33024
#define OFF_FC2B    35072
#define OFF_FC3W2   35104
#define OFF_FC3B    35424
#define OFF_GW      35440
#define OFF_FEATS_A 65536
#define OFF_FEATS_B (65536 + 8388608)

#define STRAIGHT_ATTR_IDX (65025 * 3)
#define LDS_STRIDE 33   // odd stride: conflict-free LDS (36 gave 8-way aliasing)

__device__ __forceinline__ float sigf(float x)  { return 1.0f / (1.0f + __expf(-x)); }
__device__ __forceinline__ float tanhf_(float x){ return 1.0f - 2.0f / (__expf(2.0f * x) + 1.0f); }

// ---------------- prep: pack/transpose all params into fp32 ws ----------------
__global__ void prep_kernel(const float* Wih0, const float* Whh0,
                            const float* bih0, const float* bhh0,
                            const float* Wih1, const float* Whh1,
                            const float* bih1, const float* bhh1,
                            const float* fc1w, const float* fc1b,
                            const float* convw, const float* convb,
                            const float* fc2w, const float* fc2b,
                            const float* fc3w, const float* fc3b,
                            const float* gparam, const float* eattr,
                            float* P) {
    int tid = blockIdx.x * blockDim.x + threadIdx.x;
    int stride = gridDim.x * blockDim.x;
    for (int i = tid; i < 64; i += stride) {
        int j = i >> 1, h = i & 1;
        P[OFF_PB0IF + i] = bih0[h * 32 + j] + bhh0[h * 32 + j];
        P[OFF_PB0GO + i] = bih0[(2 + h) * 32 + j] + bhh0[(2 + h) * 32 + j];
        P[OFF_PB1IF + i] = bih1[h * 32 + j] + bhh1[h * 32 + j];
        P[OFF_PB1GO + i] = bih1[(2 + h) * 32 + j] + bhh1[(2 + h) * 32 + j];
    }
    for (int idx = tid; idx < 640; idx += stride) {
        int e = idx >> 1, h = idx & 1, j = e / 10, c = e % 10;
        P[OFF_PW0I_IF + idx] = Wih0[(h * 32 + j) * 10 + c];
        P[OFF_PW0I_GO + idx] = Wih0[((2 + h) * 32 + j) * 10 + c];
    }
    for (int idx = tid; idx < 2048; idx += stride) {
        int e = idx >> 1, h = idx & 1, j = e >> 5, k = e & 31;
        P[OFF_PW0H_IF + idx] = Whh0[(h * 32 + j) * 32 + k];
        P[OFF_PW0H_GO + idx] = Whh0[((2 + h) * 32 + j) * 32 + k];
        P[OFF_PW1I_IF + idx] = Wih1[(h * 32 + j) * 32 + k];
        P[OFF_PW1I_GO + idx] = Wih1[((2 + h) * 32 + j) * 32 + k];
        P[OFF_PW1H_IF + idx] = Whh1[(h * 32 + j) * 32 + k];
        P[OFF_PW1H_GO + idx] = Whh1[((2 + h) * 32 + j) * 32 + k];
        int ch2 = e >> 5, kk = e & 31;
        P[OFF_FC1W + idx] = fc1w[(2 * ch2 + h) * 32 + kk];
        int m2 = e >> 6, ch = e & 63;
        P[OFF_FC2W2 + idx] = fc2w[(2 * m2 + h) * 64 + ch];
    }
    for (int i = tid; i < 64; i += stride) P[OFF_FC1B + i] = fc1b[i];
    for (int idx = tid; idx < 16384; idx += stride) {
        int k = idx >> 12, r = idx & 4095, e = r >> 1, h = r & 1;
        int co2 = e >> 6, ci = e & 63;
        P[OFF_CWT2 + idx] = convw[k * 4096 + ci * 64 + (2 * co2 + h)];
    }
    for (int i = tid; i < 256; i += stride) P[OFF_CB + i] = convb[i];
    for (int i = tid; i < 32;  i += stride) P[OFF_FC2B + i] = fc2b[i];
    for (int idx = tid; idx < 320; idx += stride) {
        int e = idx >> 1, h = idx & 1, oc2 = e >> 5, m = e & 31;
        P[OFF_FC3W2 + idx] = fc3w[(2 * oc2 + h) * 32 + m];
    }
    for (int i = tid; i < 10; i += stride) P[OFF_FC3B + i] = fc3b[i];
    for (int idx = tid; idx < 8; idx += stride) {
        int k = idx >> 1;
        float g = gparam[k];
        float denom = g * g + 1e-8f;
        float a = (idx & 1) ? eattr[0] : eattr[STRAIGHT_ATTR_IDX];
        P[OFF_GW + idx] = __expf(-(a * a) / denom);
    }
}

// ---------------- LSTM: 4 waves/pixel-group; wave w owns hidden units [8w,8w+8) ----------------
// launch_bounds(256,2): VGPR cap 256 — R3's (256,4) clamped to 64 VGPRs and spilled
// ~90 floats of h/c state to scratch (610 MB HBM fetch). State must stay in registers.
__global__ __launch_bounds__(256, 2)
void lstm_fc1_kernel(const float* __restrict__ x,
                     const float* __restrict__ P,
                     float* __restrict__ feats) {
    __shared__ float hx0[64 * LDS_STRIDE];
    __shared__ float hx1[64 * LDS_STRIDE];
    int p = threadIdx.x & 63;
    int subj = __builtin_amdgcn_readfirstlane(threadIdx.x >> 6);
    int n = blockIdx.x * 64 + p;
    int b = n >> 16;
    int pix = n & (NPIX - 1);
    const float* xb = x + (size_t)b * TT * CC * NPIX + pix;

    const float2* W0Iif = (const float2*)(P + OFF_PW0I_IF);
    const float2* W0Igo = (const float2*)(P + OFF_PW0I_GO);
    const float2* W0Hif = (const float2*)(P + OFF_PW0H_IF);
    const float2* W0Hgo = (const float2*)(P + OFF_PW0H_GO);
    const float2* W1Iif = (const float2*)(P + OFF_PW1I_IF);
    const float2* W1Igo = (const float2*)(P + OFF_PW1I_GO);
    const float2* W1Hif = (const float2*)(P + OFF_PW1H_IF);
    const float2* W1Hgo = (const float2*)(P + OFF_PW1H_GO);
    const float2* B0if  = (const float2*)(P + OFF_PB0IF);
    const float2* B0go  = (const float2*)(P + OFF_PB0GO);
    const float2* B1if  = (const float2*)(P + OFF_PB1IF);
    const float2* B1go  = (const float2*)(P + OFF_PB1GO);

    float h0a[32], h1a[32], c0[8], c1[8];
#pragma unroll
    for (int k = 0; k < 32; k++) { h0a[k] = 0.f; h1a[k] = 0.f; }
#pragma unroll
    for (int k = 0; k < 8; k++) { c0[k] = 0.f; c1[k] = 0.f; }

    int ldsbase = p * LDS_STRIDE;
    int myoff = ldsbase + subj * 8;

#pragma unroll 1
    for (int t = 0; t < TT; t++) {
        float xt[CC];
#pragma unroll
        for (int c = 0; c < CC; c++) xt[c] = xb[(size_t)(t * CC + c) * NPIX];

        // ---- layer 0: my 8 hidden units ----
#pragma unroll
        for (int jj = 0; jj < 8; jj++) {
            int j = subj * 8 + jj;
            float2 zif = B0if[j];
            float2 zgo = B0go[j];
            const float2* wi_if = W0Iif + j * CC;
            const float2* wi_go = W0Igo + j * CC;
#pragma unroll
            for (int c = 0; c < CC; c++) {
                float xv = xt[c];
                float2 a = wi_if[c], g = wi_go[c];
                zif.x += a.x * xv; zif.y += a.y * xv;
                zgo.x += g.x * xv; zgo.y += g.y * xv;
            }
            const float2* wh_if = W0Hif + j * HH;
            const float2* wh_go = W0Hgo + j * HH;
#pragma unroll
            for (int k = 0; k < HH; k++) {
                float hv = h0a[k];
                float2 a = wh_if[k], g = wh_go[k];
                zif.x += a.x * hv; zif.y += a.y * hv;
                zgo.x += g.x * hv; zgo.y += g.y * hv;
            }
            float cn = sigf(zif.y) * c0[jj] + sigf(zif.x) * tanhf_(zgo.x);
            c0[jj] = cn;
            hx0[myoff + jj] = sigf(zgo.y) * tanhf_(cn);
        }
        __syncthreads();
#pragma unroll
        for (int k = 0; k < HH; k++) h0a[k] = hx0[ldsbase + k];

        // ---- layer 1 ----
#pragma unroll
        for (int jj = 0; jj < 8; jj++) {
            int j = subj * 8 + jj;
            float2 zif = B1if[j];
            float2 zgo = B1go[j];
            const float2* wi_if = W1Iif + j * HH;
            const float2* wi_go = W1Igo + j * HH;
            const float2* wh_if = W1Hif + j * HH;
            const float2* wh_go = W1Hgo + j * HH;
#pragma unroll
            for (int k = 0; k < HH; k++) {
                float hv = h0a[k];
                float2 a = wi_if[k], g = wi_go[k];
                zif.x += a.x * hv; zif.y += a.y * hv;
                zgo.x += g.x * hv; zgo.y += g.y * hv;
            }
#pragma unroll
            for (int k = 0; k < HH; k++) {
                float hv = h1a[k];
                float2 a = wh_if[k], g = wh_go[k];
                zif.x += a.x * hv; zif.y += a.y * hv;
                zgo.x += g.x * hv; zgo.y += g.y * hv;
            }
            float cn = sigf(zif.y) * c1[jj] + sigf(zif.x) * tanhf_(zgo.x);
            c1[jj] = cn;
            hx1[myoff + jj] = sigf(zgo.y) * tanhf_(cn);
        }
        __syncthreads();
#pragma unroll
        for (int k = 0; k < HH; k++) h1a[k] = hx1[ldsbase + k];
    }

    // ---- fc1 + relu: my 16 channels (8 pairs) ----
    const float2* F1 = (const float2*)(P + OFF_FC1W);
    float* fb = feats + (size_t)b * WIDTH * NPIX + pix;
#pragma unroll
    for (int cc = 0; cc < 8; cc++) {
        int ch2 = subj * 8 + cc;
        float ax = P[OFF_FC1B + 2 * ch2];
        float ay = P[OFF_FC1B + 2 * ch2 + 1];
        const float2* w = F1 + ch2 * HH;
#pragma unroll
        for (int k = 0; k < HH; k++) {
            float hv = h1a[k];
            float2 ww = w[k];
            ax += ww.x * hv; ay += ww.y * hv;
        }
        fb[(size_t)(2 * ch2) * NPIX]     = fmaxf(ax, 0.f);
        fb[(size_t)(2 * ch2 + 1) * NPIX] = fmaxf(ay, 0.f);
    }
}

// ---------------- fused conv layer: u = stencil(Fin); Fout = relu(u @ W[k] + b[k]) ----------------
// (256,2): u[64]+temps needs ~130 VGPRs; (256,4)'s 128-cap risked spill.
__global__ __launch_bounds__(256, 2)
void conv_fused_kernel(const float* __restrict__ Fin, float* __restrict__ Fout,
                       const float* __restrict__ P, int k) {
    int n = blockIdx.x * 256 + threadIdx.x;
    int b = n >> 16;
    int pix = n & (NPIX - 1);
    int i = pix >> 8, j = pix & 255;
    float wstr = P[OFF_GW + 2 * k], wdiag = P[OFF_GW + 2 * k + 1];
    int oU = (i > 0)   ? -256 : 0;
    int oD = (i < 255) ?  256 : 0;
    int oL = (j > 0)   ?   -1 : 0;
    int oR = (j < 255) ?    1 : 0;
    float fu = (i > 0) ? 1.f : 0.f, fd = (i < 255) ? 1.f : 0.f;
    float fl = (j > 0) ? 1.f : 0.f, fr = (j < 255) ? 1.f : 0.f;
    float ful = fu * fl, fur = fu * fr, fdl = fd * fl, fdr = fd * fr;

    const float* fb = Fin + (size_t)b * WIDTH * NPIX + pix;
    float u[WIDTH];
#pragma unroll
    for (int ch = 0; ch < WIDTH; ch++) {
        const float* yc = fb + (size_t)ch * NPIX;
        float ss = fu * yc[oU] + fd * yc[oD] + fl * yc[oL] + fr * yc[oR];
        float sd = ful * yc[oU + oL] + fur * yc[oU + oR]
                 + fdl * yc[oD + oL] + fdr * yc[oD + oR];
        u[ch] = yc[0] + wstr * ss + wdiag * sd;
    }

    const float2* w2 = (const float2*)(P + OFF_CWT2 + k * 4096);
    const float*  cb = P + OFF_CB + k * WIDTH;
    float* ob = Fout + (size_t)b * WIDTH * NPIX + pix;
    for (int co2 = 0; co2 < 32; co2++) {
        float ax = cb[2 * co2], ay = cb[2 * co2 + 1];
        const float2* w = w2 + co2 * WIDTH;
#pragma unroll
        for (int ci = 0; ci < WIDTH; ci++) {
            float uv = u[ci];
            float2 ww = w[ci];
            ax += ww.x * uv; ay += ww.y * uv;
        }
        ob[(size_t)(2 * co2) * NPIX]     = fmaxf(ax, 0.f);
        ob[(size_t)(2 * co2 + 1) * NPIX] = fmaxf(ay, 0.f);
    }
}

// ---------------- last conv (no relu) + fc2/fc3 head ----------------
__global__ __launch_bounds__(256, 2)
void conv_head_kernel(const float* __restrict__ Fin, const float* __restrict__ P,
                      float* __restrict__ out) {
    const int k = 3;
    int n = blockIdx.x * 256 + threadIdx.x;
    int b = n >> 16;
    int pix = n & (NPIX - 1);
    int i = pix >> 8, j = pix & 255;
    float wstr = P[OFF_GW + 2 * k], wdiag = P[OFF_GW + 2 * k + 1];
    int oU = (i > 0)   ? -256 : 0;
    int oD = (i < 255) ?  256 : 0;
    int oL = (j > 0)   ?   -1 : 0;
    int oR = (j < 255) ?    1 : 0;
    float fu = (i > 0) ? 1.f : 0.f, fd = (i < 255) ? 1.f : 0.f;
    float fl = (j > 0) ? 1.f : 0.f, fr = (j < 255) ? 1.f : 0.f;
    float ful = fu * fl, fur = fu * fr, fdl = fd * fl, fdr = fd * fr;

    const float* fb = Fin + (size_t)b * WIDTH * NPIX + pix;
    float u[WIDTH];
#pragma unroll
    for (int ch = 0; ch < WIDTH; ch++) {
        const float* yc = fb + (size_t)ch * NPIX;
        float ss = fu * yc[oU] + fd * yc[oD] + fl * yc[oL] + fr * yc[oR];
        float sd = ful * yc[oU + oL] + fur * yc[oU + oR]
                 + fdl * yc[oD + oL] + fdr * yc[oD + oR];
        u[ch] = yc[0] + wstr * ss + wdiag * sd;
    }

    const float2* w2 = (const float2*)(P + OFF_CWT2 + k * 4096);
    const float*  cb = P + OFF_CB + k * WIDTH;
    float f[WIDTH];
#pragma unroll
    for (int co2 = 0; co2 < 32; co2++) {
        float ax = cb[2 * co2], ay = cb[2 * co2 + 1];
        const float2* w = w2 + co2 * WIDTH;
#pragma unroll
        for (int ci = 0; ci < WIDTH; ci++) {
            float uv = u[ci];
            float2 ww = w[ci];
            ax += ww.x * uv; ay += ww.y * uv;
        }
        f[2 * co2] = ax; f[2 * co2 + 1] = ay;
    }

    float o[OUTC];
#pragma unroll
    for (int oc = 0; oc < OUTC; oc++) o[oc] = P[OFF_FC3B + oc];
    const float2* F2 = (const float2*)(P + OFF_FC2W2);
    for (int m2 = 0; m2 < 16; m2++) {
        float ax = P[OFF_FC2B + 2 * m2], ay = P[OFF_FC2B + 2 * m2 + 1];
        const float2* w = F2 + m2 * WIDTH;
#pragma unroll
        for (int ch = 0; ch < WIDTH; ch++) {
            float fv = f[ch];
            float2 ww = w[ch];
            ax += ww.x * fv; ay += ww.y * fv;
        }
        ax = fmaxf(ax, 0.f); ay = fmaxf(ay, 0.f);
#pragma unroll
        for (int oc = 0; oc < OUTC; oc++) {
            o[oc] += P[OFF_FC3W2 + (oc >> 1) * 64 + (2 * m2) * 2 + (oc & 1)] * ax
                   + P[OFF_FC3W2 + (oc >> 1) * 64 + (2 * m2 + 1) * 2 + (oc & 1)] * ay;
        }
    }
    float* ob = out + (size_t)b * OUTC * NPIX + pix;
#pragma unroll
    for (int oc = 0; oc < OUTC; oc++) ob[(size_t)oc * NPIX] = o[oc];
}

extern "C" void kernel_launch(void* const* d_in, const int* in_sizes, int n_in,
                              void* d_out, int out_size, void* d_ws, size_t ws_size,
                              hipStream_t stream) {
    const float* x     = (const float*)d_in[0];
    const float* eattr = (const float*)d_in[3];
    const float* Wih0  = (const float*)d_in[4];
    const float* Whh0  = (const float*)d_in[5];
    const float* bih0  = (const float*)d_in[6];
    const float* bhh0  = (const float*)d_in[7];
    const float* Wih1  = (const float*)d_in[8];
    const float* Whh1  = (const float*)d_in[9];
    const float* bih1  = (const float*)d_in[10];
    const float* bhh1  = (const float*)d_in[11];
    const float* fc1w  = (const float*)d_in[12];
    const float* fc1b  = (const float*)d_in[13];
    const float* convw = (const float*)d_in[14];
    const float* convb = (const float*)d_in[15];
    const float* gparam= (const float*)d_in[16];
    const float* fc2w  = (const float*)d_in[17];
    const float* fc2b  = (const float*)d_in[18];
    const float* fc3w  = (const float*)d_in[19];
    const float* fc3b  = (const float*)d_in[20];

    float* P  = (float*)d_ws;
    float* FA = P + OFF_FEATS_A;
    float* FB = P + OFF_FEATS_B;

    prep_kernel<<<64, 256, 0, stream>>>(Wih0, Whh0, bih0, bhh0, Wih1, Whh1, bih1, bhh1,
                                        fc1w, fc1b, convw, convb, fc2w, fc2b, fc3w, fc3b,
                                        gparam, eattr, P);
    lstm_fc1_kernel<<<2048, 256, 0, stream>>>(x, P, FA);
    conv_fused_kernel<<<512, 256, 0, stream>>>(FA, FB, P, 0);
    conv_fused_kernel<<<512, 256, 0, stream>>>(FB, FA, P, 1);
    conv_fused_kernel<<<512, 256, 0, stream>>>(FA, FB, P, 2);
    conv_head_kernel<<<512, 256, 0, stream>>>(FB, P, (float*)d_out);
}

// Round 5
// 1061.057 us; speedup vs baseline: 1.7054x; 1.7054x over previous
//
#include <hip/hip_runtime.h>
#include <hip/hip_bf16.h>

#define NPIX   65536
#define TT     5
#define CC     10
#define HH     32
#define WIDTH  64
#define KW     32
#define OUTC   10

// ---- workspace layout (float offsets) ----
// LSTM staging block (copied verbatim to LDS as float4s), gate-packed (i,f,g,o):
#define OFF_L0I    0        // 1280  [j][c] float4
#define OFF_L0H    1280     // 4096  [j][k] float4
#define OFF_L1I    5376     // 4096
#define OFF_L1H    9472     // 4096
#define OFF_B0     13568    // 128   [j] float4
#define OFF_B1     13696    // 128
#define LSTM_STAGE_F4 3456  // 13824 floats / 4
// non-staged params:
#define OFF_FC1W   13824    // 2048  [ch2][k] float2
#define OFF_FC1B   15872    // 64
#define OFF_CWT2   16384    // 16384 [k][co2][ci] float2
#define OFF_CB     32768    // 256
#define OFF_FC2W2  33024    // 2048  [m2][ch] float2
#define OFF_FC2B   35072    // 32
#define OFF_FC3W4  35104    // 320   [oc2][m2] float4
#define OFF_FC3B   35424    // 16
#define OFF_GW     35440    // 8
#define OFF_FEATS_A 36864
#define OFF_FEATS_B (36864 + 8388608)
// total footprint 16814080 floats < R3/R4's 16842752 (known-safe ws size)

#define STRAIGHT_ATTR_IDX (65025 * 3)
#define HXS 33   // exchange stride: odd => conflict-free

__device__ __forceinline__ float sigf(float x)  { return 1.0f / (1.0f + __expf(-x)); }
__device__ __forceinline__ float tanhf_(float x){ return 1.0f - 2.0f / (__expf(2.0f * x) + 1.0f); }

// ---------------- prep: pack/transpose all params into fp32 ws ----------------
__global__ __launch_bounds__(256, 1)
void prep_kernel(const float* Wih0, const float* Whh0,
                 const float* bih0, const float* bhh0,
                 const float* Wih1, const float* Whh1,
                 const float* bih1, const float* bhh1,
                 const float* fc1w, const float* fc1b,
                 const float* convw, const float* convb,
                 const float* fc2w, const float* fc2b,
                 const float* fc3w, const float* fc3b,
                 const float* gparam, const float* eattr,
                 float* P) {
    int tid = blockIdx.x * blockDim.x + threadIdx.x;
    int stride = gridDim.x * blockDim.x;
    // L0I [j][c] float4 of gates (i,f,g,o)
    for (int idx = tid; idx < 1280; idx += stride) {
        int g = idx & 3, e = idx >> 2, j = e / 10, c = e % 10;
        P[OFF_L0I + idx] = Wih0[(g * 32 + j) * 10 + c];
    }
    for (int idx = tid; idx < 4096; idx += stride) {
        int g = idx & 3, e = idx >> 2, j = e >> 5, k = e & 31;
        P[OFF_L0H + idx] = Whh0[(g * 32 + j) * 32 + k];
        P[OFF_L1I + idx] = Wih1[(g * 32 + j) * 32 + k];
        P[OFF_L1H + idx] = Whh1[(g * 32 + j) * 32 + k];
    }
    for (int idx = tid; idx < 128; idx += stride) {
        int g = idx & 3, j = idx >> 2;
        P[OFF_B0 + idx] = bih0[g * 32 + j] + bhh0[g * 32 + j];
        P[OFF_B1 + idx] = bih1[g * 32 + j] + bhh1[g * 32 + j];
    }
    // fc1 [ch2][k] float2
    for (int idx = tid; idx < 2048; idx += stride) {
        int e = idx >> 1, h = idx & 1, ch2 = e >> 5, kk = e & 31;
        P[OFF_FC1W + idx] = fc1w[(2 * ch2 + h) * 32 + kk];
        int m2 = e >> 6, ch = e & 63;
        P[OFF_FC2W2 + idx] = fc2w[(2 * m2 + h) * 64 + ch];
    }
    for (int i = tid; i < 64; i += stride) P[OFF_FC1B + i] = fc1b[i];
    // conv_w[k][ci][co] -> [k][co2][ci] float2
    for (int idx = tid; idx < 16384; idx += stride) {
        int k = idx >> 12, r = idx & 4095, e = r >> 1, h = r & 1;
        int co2 = e >> 6, ci = e & 63;
        P[OFF_CWT2 + idx] = convw[k * 4096 + ci * 64 + (2 * co2 + h)];
    }
    for (int i = tid; i < 256; i += stride) P[OFF_CB + i] = convb[i];
    for (int i = tid; i < 32;  i += stride) P[OFF_FC2B + i] = fc2b[i];
    // fc3 [oc2][m2] float4: (w[2oc2][2m2], w[2oc2+1][2m2], w[2oc2][2m2+1], w[2oc2+1][2m2+1])
    for (int idx = tid; idx < 320; idx += stride) {
        int q = idx & 3, e = idx >> 2, oc2 = e >> 4, m2 = e & 15;
        int oc = 2 * oc2 + (q & 1), m = 2 * m2 + (q >> 1);
        P[OFF_FC3W4 + idx] = fc3w[oc * 32 + m];
    }
    for (int i = tid; i < 10; i += stride) P[OFF_FC3B + i] = fc3b[i];
    for (int idx = tid; idx < 8; idx += stride) {
        int k = idx >> 1;
        float g = gparam[k];
        float denom = g * g + 1e-8f;
        float a = (idx & 1) ? eattr[0] : eattr[STRAIGHT_ATTR_IDX];
        P[OFF_GW + idx] = __expf(-(a * a) / denom);
    }
}

// ---------------- LSTM: 64 px/block, 4 waves, wave w owns units [8w,8w+8) ----------------
// Weights in LDS (float4 gate-packed, broadcast ds_read_b128); h exchange via one
// shared buffer (stride 33). (256,1): any 2nd arg > 1 makes the backend spill.
__global__ __launch_bounds__(256, 1)
void lstm_fc1_kernel(const float* __restrict__ x,
                     const float* __restrict__ P,
                     float* __restrict__ feats) {
    __shared__ float4 LW[LSTM_STAGE_F4];   // 55296 B
    __shared__ float  HX[64 * HXS];        // 8448 B   (total 63744 <= 64K)

    // stage weights
    {
        const float4* P4 = (const float4*)P;
        for (int i = threadIdx.x; i < LSTM_STAGE_F4; i += 256) LW[i] = P4[i];
    }
    __syncthreads();

    int p = threadIdx.x & 63;
    int subj = __builtin_amdgcn_readfirstlane(threadIdx.x >> 6);
    int n = blockIdx.x * 64 + p;
    int b = n >> 16;
    int pix = n & (NPIX - 1);
    const float* xb = x + (size_t)b * TT * CC * NPIX + pix;

    const float4* W0I = LW;            // [j*10+c]
    const float4* W0H = LW + 320;      // [j*32+k]
    const float4* W1I = LW + 1344;
    const float4* W1H = LW + 2368;
    const float4* B0  = LW + 3392;     // [j]
    const float4* B1  = LW + 3424;

    float h0a[HH], h1a[HH], c0[8], c1[8];
#pragma unroll
    for (int k = 0; k < HH; k++) { h0a[k] = 0.f; h1a[k] = 0.f; }
#pragma unroll
    for (int k = 0; k < 8; k++) { c0[k] = 0.f; c1[k] = 0.f; }

    int ldsbase = p * HXS;
    int myoff = ldsbase + subj * 8;

#pragma unroll 1
    for (int t = 0; t < TT; t++) {
        float xt[CC];
#pragma unroll
        for (int c = 0; c < CC; c++) xt[c] = xb[(size_t)(t * CC + c) * NPIX];

        // ---- layer 0: my 8 units ----
        float hn[8];
#pragma unroll
        for (int jj = 0; jj < 8; jj++) {
            int j = subj * 8 + jj;
            float4 z = B0[j];
            const float4* wi = W0I + j * CC;
#pragma unroll
            for (int c = 0; c < CC; c++) {
                float xv = xt[c];
                float4 w = wi[c];
                z.x += w.x * xv; z.y += w.y * xv;
                z.z += w.z * xv; z.w += w.w * xv;
            }
            const float4* wh = W0H + j * HH;
#pragma unroll
            for (int k = 0; k < HH; k++) {
                float hv = h0a[k];
                float4 w = wh[k];
                z.x += w.x * hv; z.y += w.y * hv;
                z.z += w.z * hv; z.w += w.w * hv;
            }
            float cn = sigf(z.y) * c0[jj] + sigf(z.x) * tanhf_(z.z);
            c0[jj] = cn;
            hn[jj] = sigf(z.w) * tanhf_(cn);
        }
#pragma unroll
        for (int jj = 0; jj < 8; jj++) HX[myoff + jj] = hn[jj];
        __syncthreads();
#pragma unroll
        for (int k = 0; k < HH; k++) h0a[k] = HX[ldsbase + k];
        __syncthreads();

        // ---- layer 1 ----
#pragma unroll
        for (int jj = 0; jj < 8; jj++) {
            int j = subj * 8 + jj;
            float4 z = B1[j];
            const float4* wi = W1I + j * HH;
            const float4* wh = W1H + j * HH;
#pragma unroll
            for (int k = 0; k < HH; k++) {
                float hv = h0a[k];
                float4 w = wi[k];
                z.x += w.x * hv; z.y += w.y * hv;
                z.z += w.z * hv; z.w += w.w * hv;
            }
#pragma unroll
            for (int k = 0; k < HH; k++) {
                float hv = h1a[k];
                float4 w = wh[k];
                z.x += w.x * hv; z.y += w.y * hv;
                z.z += w.z * hv; z.w += w.w * hv;
            }
            float cn = sigf(z.y) * c1[jj] + sigf(z.x) * tanhf_(z.z);
            c1[jj] = cn;
            hn[jj] = sigf(z.w) * tanhf_(cn);
        }
#pragma unroll
        for (int jj = 0; jj < 8; jj++) HX[myoff + jj] = hn[jj];
        __syncthreads();
#pragma unroll
        for (int k = 0; k < HH; k++) h1a[k] = HX[ldsbase + k];
        __syncthreads();
    }

    // ---- fc1 + relu: my 16 channels (weights from global, once) ----
    const float2* F1 = (const float2*)(P + OFF_FC1W);
    float* fb = feats + (size_t)b * WIDTH * NPIX + pix;
#pragma unroll 1
    for (int cc = 0; cc < 8; cc++) {
        int ch2 = subj * 8 + cc;
        float ax = P[OFF_FC1B + 2 * ch2];
        float ay = P[OFF_FC1B + 2 * ch2 + 1];
        const float2* w = F1 + ch2 * HH;
#pragma unroll
        for (int k = 0; k < HH; k++) {
            float hv = h1a[k];
            float2 ww = w[k];
            ax += ww.x * hv; ay += ww.y * hv;
        }
        fb[(size_t)(2 * ch2) * NPIX]     = fmaxf(ax, 0.f);
        fb[(size_t)(2 * ch2 + 1) * NPIX] = fmaxf(ay, 0.f);
    }
}

// ---------------- fused conv layer: u = stencil(Fin); Fout = relu(u @ W[k] + b[k]) ----------------
// Taps use fixed immediate offsets * 0/1 masks (OOB reads stay inside ws, finite, x0).
__global__ __launch_bounds__(256, 1)
void conv_fused_kernel(const float* __restrict__ Fin, float* __restrict__ Fout,
                       const float* __restrict__ P, int k) {
    __shared__ float4 CW[1024];   // [co2][ci2]
    __shared__ float  CB[64];
    {
        const float4* src = (const float4*)(P + OFF_CWT2 + k * 4096);
        for (int i = threadIdx.x; i < 1024; i += 256) CW[i] = src[i];
        if (threadIdx.x < 64) CB[threadIdx.x] = P[OFF_CB + k * 64 + threadIdx.x];
    }
    __syncthreads();

    int n = blockIdx.x * 256 + threadIdx.x;
    int b = n >> 16;
    int pix = n & (NPIX - 1);
    int i = pix >> 8, j = pix & 255;
    float wstr = P[OFF_GW + 2 * k], wdiag = P[OFF_GW + 2 * k + 1];
    float fu = (i > 0) ? wstr : 0.f, fd = (i < 255) ? wstr : 0.f;
    float fl = (j > 0) ? wstr : 0.f, fr = (j < 255) ? wstr : 0.f;
    float ful = (i > 0 && j > 0) ? wdiag : 0.f, fur = (i > 0 && j < 255) ? wdiag : 0.f;
    float fdl = (i < 255 && j > 0) ? wdiag : 0.f, fdr = (i < 255 && j < 255) ? wdiag : 0.f;

    const float* fb = Fin + (size_t)b * WIDTH * NPIX + pix;
    float u[WIDTH];
#pragma unroll
    for (int ch = 0; ch < WIDTH; ch++) {
        const float* yc = fb + (size_t)ch * NPIX;
        float v = yc[0];
        v += fu * yc[-256] + fd * yc[256] + fl * yc[-1] + fr * yc[1];
        v += ful * yc[-257] + fur * yc[-255] + fdl * yc[255] + fdr * yc[257];
        u[ch] = v;
    }

    float* ob = Fout + (size_t)b * WIDTH * NPIX + pix;
#pragma unroll 1
    for (int co2 = 0; co2 < 32; co2++) {
        float ax = CB[2 * co2], ay = CB[2 * co2 + 1];
        const float4* w = CW + co2 * 32;
#pragma unroll
        for (int ci2 = 0; ci2 < 32; ci2++) {
            float4 q = w[ci2];
            float u0 = u[2 * ci2], u1 = u[2 * ci2 + 1];
            ax += q.x * u0 + q.z * u1;
            ay += q.y * u0 + q.w * u1;
        }
        ob[(size_t)(2 * co2) * NPIX]     = fmaxf(ax, 0.f);
        ob[(size_t)(2 * co2 + 1) * NPIX] = fmaxf(ay, 0.f);
    }
}

// ---------------- last conv (no relu) + fc2/fc3 head ----------------
__global__ __launch_bounds__(256, 1)
void conv_head_kernel(const float* __restrict__ Fin, const float* __restrict__ P,
                      float* __restrict__ out) {
    const int k = 3;
    __shared__ float4 CW3[1024];
    __shared__ float  CB3[64];
    __shared__ float4 F2W[512];   // [m2][ch2]
    __shared__ float  F2B[32];
    __shared__ float4 F3W[80];    // [oc2][m2]
    __shared__ float  F3B[12];
    {
        const float4* s1 = (const float4*)(P + OFF_CWT2 + k * 4096);
        for (int i = threadIdx.x; i < 1024; i += 256) CW3[i] = s1[i];
        const float4* s2 = (const float4*)(P + OFF_FC2W2);
        for (int i = threadIdx.x; i < 512; i += 256) F2W[i] = s2[i];
        const float4* s3 = (const float4*)(P + OFF_FC3W4);
        if (threadIdx.x < 80) F3W[threadIdx.x] = s3[threadIdx.x];
        if (threadIdx.x < 64) CB3[threadIdx.x] = P[OFF_CB + k * 64 + threadIdx.x];
        if (threadIdx.x < 32) F2B[threadIdx.x] = P[OFF_FC2B + threadIdx.x];
        if (threadIdx.x < 10) F3B[threadIdx.x] = P[OFF_FC3B + threadIdx.x];
    }
    __syncthreads();

    int n = blockIdx.x * 256 + threadIdx.x;
    int b = n >> 16;
    int pix = n & (NPIX - 1);
    int i = pix >> 8, j = pix & 255;
    float wstr = P[OFF_GW + 2 * k], wdiag = P[OFF_GW + 2 * k + 1];
    float fu = (i > 0) ? wstr : 0.f, fd = (i < 255) ? wstr : 0.f;
    float fl = (j > 0) ? wstr : 0.f, fr = (j < 255) ? wstr : 0.f;
    float ful = (i > 0 && j > 0) ? wdiag : 0.f, fur = (i > 0 && j < 255) ? wdiag : 0.f;
    float fdl = (i < 255 && j > 0) ? wdiag : 0.f, fdr = (i < 255 && j < 255) ? wdiag : 0.f;

    const float* fb = Fin + (size_t)b * WIDTH * NPIX + pix;
    float u[WIDTH];
#pragma unroll
    for (int ch = 0; ch < WIDTH; ch++) {
        const float* yc = fb + (size_t)ch * NPIX;
        float v = yc[0];
        v += fu * yc[-256] + fd * yc[256] + fl * yc[-1] + fr * yc[1];
        v += ful * yc[-257] + fur * yc[-255] + fdl * yc[255] + fdr * yc[257];
        u[ch] = v;
    }

    // f = u @ W[3] + b[3]  (no relu) — co2 unrolled so f[] stays in registers
    float f[WIDTH];
#pragma unroll
    for (int co2 = 0; co2 < 32; co2++) {
        float ax = CB3[2 * co2], ay = CB3[2 * co2 + 1];
        const float4* w = CW3 + co2 * 32;
#pragma unroll
        for (int ci2 = 0; ci2 < 32; ci2++) {
            float4 q = w[ci2];
            float u0 = u[2 * ci2], u1 = u[2 * ci2 + 1];
            ax += q.x * u0 + q.z * u1;
            ay += q.y * u0 + q.w * u1;
        }
        f[2 * co2] = ax; f[2 * co2 + 1] = ay;
    }

    float2 oo[5];
#pragma unroll
    for (int oc2 = 0; oc2 < 5; oc2++) oo[oc2] = make_float2(F3B[2 * oc2], F3B[2 * oc2 + 1]);
#pragma unroll 1
    for (int m2 = 0; m2 < 16; m2++) {
        float ax = F2B[2 * m2], ay = F2B[2 * m2 + 1];
        const float4* w = F2W + m2 * 32;
#pragma unroll
        for (int ch2 = 0; ch2 < 32; ch2++) {
            float4 q = w[ch2];
            float f0 = f[2 * ch2], f1 = f[2 * ch2 + 1];
            ax += q.x * f0 + q.z * f1;
            ay += q.y * f0 + q.w * f1;
        }
        ax = fmaxf(ax, 0.f); ay = fmaxf(ay, 0.f);
#pragma unroll
        for (int oc2 = 0; oc2 < 5; oc2++) {
            float4 q = F3W[oc2 * 16 + m2];
            oo[oc2].x += q.x * ax + q.z * ay;
            oo[oc2].y += q.y * ax + q.w * ay;
        }
    }
    float* ob = out + (size_t)b * OUTC * NPIX + pix;
#pragma unroll
    for (int oc2 = 0; oc2 < 5; oc2++) {
        ob[(size_t)(2 * oc2) * NPIX]     = oo[oc2].x;
        ob[(size_t)(2 * oc2 + 1) * NPIX] = oo[oc2].y;
    }
}

extern "C" void kernel_launch(void* const* d_in, const int* in_sizes, int n_in,
                              void* d_out, int out_size, void* d_ws, size_t ws_size,
                              hipStream_t stream) {
    const float* x     = (const float*)d_in[0];
    const float* eattr = (const float*)d_in[3];
    const float* Wih0  = (const float*)d_in[4];
    const float* Whh0  = (const float*)d_in[5];
    const float* bih0  = (const float*)d_in[6];
    const float* bhh0  = (const float*)d_in[7];
    const float* Wih1  = (const float*)d_in[8];
    const float* Whh1  = (const float*)d_in[9];
    const float* bih1  = (const float*)d_in[10];
    const float* bhh1  = (const float*)d_in[11];
    const float* fc1w  = (const float*)d_in[12];
    const float* fc1b  = (const float*)d_in[13];
    const float* convw = (const float*)d_in[14];
    const float* convb = (const float*)d_in[15];
    const float* gparam= (const float*)d_in[16];
    const float* fc2w  = (const float*)d_in[17];
    const float* fc2b  = (const float*)d_in[18];
    const float* fc3w  = (const float*)d_in[19];
    const float* fc3b  = (const float*)d_in[20];

    float* P  = (float*)d_ws;
    float* FA = P + OFF_FEATS_A;
    float* FB = P + OFF_FEATS_B;

    prep_kernel<<<64, 256, 0, stream>>>(Wih0, Whh0, bih0, bhh0, Wih1, Whh1, bih1, bhh1,
                                        fc1w, fc1b, convw, convb, fc2w, fc2b, fc3w, fc3b,
                                        gparam, eattr, P);
    lstm_fc1_kernel<<<2048, 256, 0, stream>>>(x, P, FA);
    conv_fused_kernel<<<512, 256, 0, stream>>>(FA, FB, P, 0);
    conv_fused_kernel<<<512, 256, 0, stream>>>(FB, FA, P, 1);
    conv_fused_kernel<<<512, 256, 0, stream>>>(FA, FB, P, 2);
    conv_head_kernel<<<512, 256, 0, stream>>>(FB, P, (float*)d_out);
}

// Round 6
// 841.888 us; speedup vs baseline: 2.1493x; 1.2603x over previous
//
#include <hip/hip_runtime.h>
#include <hip/hip_bf16.h>

#define NPIX   65536
#define TT     5
#define CC     10
#define HH     32
#define WIDTH  64
#define KW     32
#define OUTC   10

// ---- workspace layout (float offsets) ----
#define OFF_L0I    0        // 1280  [j][c] float4 gates (i,f,g,o)
#define OFF_L0H    1280     // 4096  [j][k] float4
#define OFF_L1I    5376     // 4096
#define OFF_L1H    9472     // 4096
#define OFF_B0     13568    // 128
#define OFF_B1     13696    // 128
#define LSTM_STAGE_F4 3456  // 13824 floats / 4
#define OFF_FC1W   13824    // 2048  [ch2][k] float2
#define OFF_FC1B   15872    // 64
#define OFF_CWT2   16384    // 16384 [k][co2][ci] float2
#define OFF_CB     32768    // 256
#define OFF_FC2W2  33024    // 2048  [m2][ch] float2
#define OFF_FC2B   35072    // 32
#define OFF_FC3W4  35104    // 320   [oc2][m2] float4
#define OFF_FC3B   35424    // 16
#define OFF_GW     35440    // 8
#define OFF_FEATS_A 36864
#define OFF_FEATS_B (36864 + 8388608)

#define STRAIGHT_ATTR_IDX (65025 * 3)

__device__ __forceinline__ float sigf(float x)  { return 1.0f / (1.0f + __expf(-x)); }
__device__ __forceinline__ float tanhf_(float x){ return 1.0f - 2.0f / (__expf(2.0f * x) + 1.0f); }

// ---------------- prep: pack/transpose all params into fp32 ws (same as R5) ----------------
__global__ __launch_bounds__(256, 1)
void prep_kernel(const float* Wih0, const float* Whh0,
                 const float* bih0, const float* bhh0,
                 const float* Wih1, const float* Whh1,
                 const float* bih1, const float* bhh1,
                 const float* fc1w, const float* fc1b,
                 const float* convw, const float* convb,
                 const float* fc2w, const float* fc2b,
                 const float* fc3w, const float* fc3b,
                 const float* gparam, const float* eattr,
                 float* P) {
    int tid = blockIdx.x * blockDim.x + threadIdx.x;
    int stride = gridDim.x * blockDim.x;
    for (int idx = tid; idx < 1280; idx += stride) {
        int g = idx & 3, e = idx >> 2, j = e / 10, c = e % 10;
        P[OFF_L0I + idx] = Wih0[(g * 32 + j) * 10 + c];
    }
    for (int idx = tid; idx < 4096; idx += stride) {
        int g = idx & 3, e = idx >> 2, j = e >> 5, k = e & 31;
        P[OFF_L0H + idx] = Whh0[(g * 32 + j) * 32 + k];
        P[OFF_L1I + idx] = Wih1[(g * 32 + j) * 32 + k];
        P[OFF_L1H + idx] = Whh1[(g * 32 + j) * 32 + k];
    }
    for (int idx = tid; idx < 128; idx += stride) {
        int g = idx & 3, j = idx >> 2;
        P[OFF_B0 + idx] = bih0[g * 32 + j] + bhh0[g * 32 + j];
        P[OFF_B1 + idx] = bih1[g * 32 + j] + bhh1[g * 32 + j];
    }
    for (int idx = tid; idx < 2048; idx += stride) {
        int e = idx >> 1, h = idx & 1, ch2 = e >> 5, kk = e & 31;
        P[OFF_FC1W + idx] = fc1w[(2 * ch2 + h) * 32 + kk];
        int m2 = e >> 6, ch = e & 63;
        P[OFF_FC2W2 + idx] = fc2w[(2 * m2 + h) * 64 + ch];
    }
    for (int i = tid; i < 64; i += stride) P[OFF_FC1B + i] = fc1b[i];
    for (int idx = tid; idx < 16384; idx += stride) {
        int k = idx >> 12, r = idx & 4095, e = r >> 1, h = r & 1;
        int co2 = e >> 6, ci = e & 63;
        P[OFF_CWT2 + idx] = convw[k * 4096 + ci * 64 + (2 * co2 + h)];
    }
    for (int i = tid; i < 256; i += stride) P[OFF_CB + i] = convb[i];
    for (int i = tid; i < 32;  i += stride) P[OFF_FC2B + i] = fc2b[i];
    for (int idx = tid; idx < 320; idx += stride) {
        int q = idx & 3, e = idx >> 2, oc2 = e >> 4, m2 = e & 15;
        int oc = 2 * oc2 + (q & 1), m = 2 * m2 + (q >> 1);
        P[OFF_FC3W4 + idx] = fc3w[oc * 32 + m];
    }
    for (int i = tid; i < 10; i += stride) P[OFF_FC3B + i] = fc3b[i];
    for (int idx = tid; idx < 8; idx += stride) {
        int k = idx >> 1;
        float g = gparam[k];
        float denom = g * g + 1e-8f;
        float a = (idx & 1) ? eattr[0] : eattr[STRAIGHT_ATTR_IDX];
        P[OFF_GW + idx] = __expf(-(a * a) / denom);
    }
}

// ---------------- LSTM: 512 thr (8 waves), 128 px/block, 2 px/lane, 4 units/wave ----------------
// Each broadcast ds_read_b128 (one float4 weight) now feeds 8 FMAs (4 gates x 2 px).
// h-exchange: HX[k][64px] transposed (conflict-free), two 64-px phases.
__global__ __launch_bounds__(512, 1)
void lstm_fc1_kernel(const float* __restrict__ x,
                     const float* __restrict__ P,
                     float* __restrict__ feats) {
    __shared__ float4 LW[LSTM_STAGE_F4];   // 55296 B
    __shared__ float  HX[32 * 64];         // 8192 B   (total 63488)
    {
        const float4* P4 = (const float4*)P;
        for (int i = threadIdx.x; i < LSTM_STAGE_F4; i += 512) LW[i] = P4[i];
    }
    __syncthreads();

    int p = threadIdx.x & 63;
    int subw = __builtin_amdgcn_readfirstlane((int)(threadIdx.x >> 6)); // 0..7
    int n0 = blockIdx.x * 128 + p;        // px0; px1 = px0 + 64 (same b: 65536 % 128 == 0)
    int b = n0 >> 16;
    int pix = n0 & (NPIX - 1);
    const float* xb = x + (size_t)b * TT * CC * NPIX + pix;

    const float4* W0I = LW;            // [j*10+c]
    const float4* W0H = LW + 320;      // [j*32+k]
    const float4* W1I = LW + 1344;
    const float4* W1H = LW + 2368;
    const float4* B0  = LW + 3392;
    const float4* B1  = LW + 3424;

    float h0a0[HH], h0a1[HH], h1a0[HH], h1a1[HH];
    float c00[4], c01[4], c10[4], c11[4];
#pragma unroll
    for (int k = 0; k < HH; k++) { h0a0[k] = 0.f; h0a1[k] = 0.f; h1a0[k] = 0.f; h1a1[k] = 0.f; }
#pragma unroll
    for (int k = 0; k < 4; k++) { c00[k] = 0.f; c01[k] = 0.f; c10[k] = 0.f; c11[k] = 0.f; }

#pragma unroll 1
    for (int t = 0; t < TT; t++) {
        float xt0[CC], xt1[CC];
#pragma unroll
        for (int c = 0; c < CC; c++) {
            xt0[c] = xb[(size_t)(t * CC + c) * NPIX];
            xt1[c] = xb[(size_t)(t * CC + c) * NPIX + 64];
        }

        float hn0[4], hn1[4];
        // ---- layer 0: my 4 units, both px ----
#pragma unroll
        for (int jj = 0; jj < 4; jj++) {
            int j = subw * 4 + jj;
            float4 z0 = B0[j];
            float4 z1 = z0;
            const float4* wi = W0I + j * CC;
#pragma unroll
            for (int c = 0; c < CC; c++) {
                float4 q = wi[c];
                float a = xt0[c], bv = xt1[c];
                z0.x += q.x * a; z0.y += q.y * a; z0.z += q.z * a; z0.w += q.w * a;
                z1.x += q.x * bv; z1.y += q.y * bv; z1.z += q.z * bv; z1.w += q.w * bv;
            }
            const float4* wh = W0H + j * HH;
#pragma unroll
            for (int k = 0; k < HH; k++) {
                float4 q = wh[k];
                float a = h0a0[k], bv = h0a1[k];
                z0.x += q.x * a; z0.y += q.y * a; z0.z += q.z * a; z0.w += q.w * a;
                z1.x += q.x * bv; z1.y += q.y * bv; z1.z += q.z * bv; z1.w += q.w * bv;
            }
            float cn0 = sigf(z0.y) * c00[jj] + sigf(z0.x) * tanhf_(z0.z);
            c00[jj] = cn0; hn0[jj] = sigf(z0.w) * tanhf_(cn0);
            float cn1 = sigf(z1.y) * c01[jj] + sigf(z1.x) * tanhf_(z1.z);
            c01[jj] = cn1; hn1[jj] = sigf(z1.w) * tanhf_(cn1);
        }
        // ---- exchange L0, phased ----
#pragma unroll
        for (int jj = 0; jj < 4; jj++) HX[(subw * 4 + jj) * 64 + p] = hn0[jj];
        __syncthreads();
#pragma unroll
        for (int k = 0; k < HH; k++) h0a0[k] = HX[k * 64 + p];
        __syncthreads();
#pragma unroll
        for (int jj = 0; jj < 4; jj++) HX[(subw * 4 + jj) * 64 + p] = hn1[jj];
        __syncthreads();
#pragma unroll
        for (int k = 0; k < HH; k++) h0a1[k] = HX[k * 64 + p];
        __syncthreads();

        // ---- layer 1 ----
#pragma unroll
        for (int jj = 0; jj < 4; jj++) {
            int j = subw * 4 + jj;
            float4 z0 = B1[j];
            float4 z1 = z0;
            const float4* wi = W1I + j * HH;
#pragma unroll
            for (int k = 0; k < HH; k++) {
                float4 q = wi[k];
                float a = h0a0[k], bv = h0a1[k];
                z0.x += q.x * a; z0.y += q.y * a; z0.z += q.z * a; z0.w += q.w * a;
                z1.x += q.x * bv; z1.y += q.y * bv; z1.z += q.z * bv; z1.w += q.w * bv;
            }
            const float4* wh = W1H + j * HH;
#pragma unroll
            for (int k = 0; k < HH; k++) {
                float4 q = wh[k];
                float a = h1a0[k], bv = h1a1[k];
                z0.x += q.x * a; z0.y += q.y * a; z0.z += q.z * a; z0.w += q.w * a;
                z1.x += q.x * bv; z1.y += q.y * bv; z1.z += q.z * bv; z1.w += q.w * bv;
            }
            float cn0 = sigf(z0.y) * c10[jj] + sigf(z0.x) * tanhf_(z0.z);
            c10[jj] = cn0; hn0[jj] = sigf(z0.w) * tanhf_(cn0);
            float cn1 = sigf(z1.y) * c11[jj] + sigf(z1.x) * tanhf_(z1.z);
            c11[jj] = cn1; hn1[jj] = sigf(z1.w) * tanhf_(cn1);
        }
        // ---- exchange L1, phased ----
#pragma unroll
        for (int jj = 0; jj < 4; jj++) HX[(subw * 4 + jj) * 64 + p] = hn0[jj];
        __syncthreads();
#pragma unroll
        for (int k = 0; k < HH; k++) h1a0[k] = HX[k * 64 + p];
        __syncthreads();
#pragma unroll
        for (int jj = 0; jj < 4; jj++) HX[(subw * 4 + jj) * 64 + p] = hn1[jj];
        __syncthreads();
#pragma unroll
        for (int k = 0; k < HH; k++) h1a1[k] = HX[k * 64 + p];
        __syncthreads();
    }

    // ---- fc1 + relu: my 8 channels (4 pairs), both px; weights global (once) ----
    const float2* F1 = (const float2*)(P + OFF_FC1W);
    float* fb = feats + (size_t)b * WIDTH * NPIX + pix;
#pragma unroll
    for (int cc = 0; cc < 4; cc++) {
        int ch2 = subw * 4 + cc;
        float ax0 = P[OFF_FC1B + 2 * ch2];
        float ay0 = P[OFF_FC1B + 2 * ch2 + 1];
        float ax1 = ax0, ay1 = ay0;
        const float2* wv = F1 + ch2 * HH;
#pragma unroll
        for (int k = 0; k < HH; k++) {
            float2 q = wv[k];
            float a = h1a0[k], bv = h1a1[k];
            ax0 += q.x * a; ay0 += q.y * a;
            ax1 += q.x * bv; ay1 += q.y * bv;
        }
        fb[(size_t)(2 * ch2) * NPIX]          = fmaxf(ax0, 0.f);
        fb[(size_t)(2 * ch2 + 1) * NPIX]      = fmaxf(ay0, 0.f);
        fb[(size_t)(2 * ch2) * NPIX + 64]     = fmaxf(ax1, 0.f);
        fb[(size_t)(2 * ch2 + 1) * NPIX + 64] = fmaxf(ay1, 0.f);
    }
}

// ---------------- fused conv layer, 2 px/thread (128 thr, 256 px/block) ----------------
__global__ __launch_bounds__(128, 1)
void conv_fused_kernel(const float* __restrict__ Fin, float* __restrict__ Fout,
                       const float* __restrict__ P, int k) {
    __shared__ float4 CW[1024];   // [co2][ci2]
    __shared__ float  CB[64];
    {
        const float4* src = (const float4*)(P + OFF_CWT2 + k * 4096);
        for (int i = threadIdx.x; i < 1024; i += 128) CW[i] = src[i];
        if (threadIdx.x < 64) CB[threadIdx.x] = P[OFF_CB + k * 64 + threadIdx.x];
    }
    __syncthreads();

    int n0 = blockIdx.x * 256 + threadIdx.x;  // px1 = px0 + 128, same b & row
    int b = n0 >> 16;
    int pix0 = n0 & (NPIX - 1);
    int pix1 = pix0 + 128;
    int i0 = pix0 >> 8, j0 = pix0 & 255, j1 = j0 + 128;
    float wstr = P[OFF_GW + 2 * k], wdiag = P[OFF_GW + 2 * k + 1];
    float fu = (i0 > 0) ? wstr : 0.f, fd = (i0 < 255) ? wstr : 0.f;
    float fl0 = (j0 > 0) ? wstr : 0.f, fr0 = (j0 < 255) ? wstr : 0.f;
    float fl1 = (j1 > 0) ? wstr : 0.f, fr1 = (j1 < 255) ? wstr : 0.f;
    float fu_ = (i0 > 0) ? wdiag : 0.f, fd_ = (i0 < 255) ? wdiag : 0.f;
    float ful0 = (j0 > 0) ? fu_ : 0.f, fur0 = (j0 < 255) ? fu_ : 0.f;
    float fdl0 = (j0 > 0) ? fd_ : 0.f, fdr0 = (j0 < 255) ? fd_ : 0.f;
    float ful1 = (j1 > 0) ? fu_ : 0.f, fur1 = (j1 < 255) ? fu_ : 0.f;
    float fdl1 = (j1 > 0) ? fd_ : 0.f, fdr1 = (j1 < 255) ? fd_ : 0.f;

    const float* fb = Fin + (size_t)b * WIDTH * NPIX;
    float u0[WIDTH], u1[WIDTH];
#pragma unroll
    for (int ch = 0; ch < WIDTH; ch++) {
        const float* yc0 = fb + (size_t)ch * NPIX + pix0;
        float v0 = yc0[0];
        v0 += fu * yc0[-256] + fd * yc0[256] + fl0 * yc0[-1] + fr0 * yc0[1];
        v0 += ful0 * yc0[-257] + fur0 * yc0[-255] + fdl0 * yc0[255] + fdr0 * yc0[257];
        u0[ch] = v0;
        const float* yc1 = yc0 + 128;
        float v1 = yc1[0];
        v1 += fu * yc1[-256] + fd * yc1[256] + fl1 * yc1[-1] + fr1 * yc1[1];
        v1 += ful1 * yc1[-257] + fur1 * yc1[-255] + fdl1 * yc1[255] + fdr1 * yc1[257];
        u1[ch] = v1;
    }

    float* ob = Fout + (size_t)b * WIDTH * NPIX;
#pragma unroll 1
    for (int co2 = 0; co2 < 32; co2++) {
        float bx = CB[2 * co2], by = CB[2 * co2 + 1];
        float ax0 = bx, ay0 = by, ax1 = bx, ay1 = by;
        const float4* wv = CW + co2 * 32;
#pragma unroll
        for (int ci2 = 0; ci2 < 32; ci2++) {
            float4 q = wv[ci2];
            float a0 = u0[2 * ci2], a1 = u0[2 * ci2 + 1];
            float b0 = u1[2 * ci2], b1 = u1[2 * ci2 + 1];
            ax0 += q.x * a0 + q.z * a1;
            ay0 += q.y * a0 + q.w * a1;
            ax1 += q.x * b0 + q.z * b1;
            ay1 += q.y * b0 + q.w * b1;
        }
        ob[(size_t)(2 * co2) * NPIX + pix0]     = fmaxf(ax0, 0.f);
        ob[(size_t)(2 * co2 + 1) * NPIX + pix0] = fmaxf(ay0, 0.f);
        ob[(size_t)(2 * co2) * NPIX + pix1]     = fmaxf(ax1, 0.f);
        ob[(size_t)(2 * co2 + 1) * NPIX + pix1] = fmaxf(ay1, 0.f);
    }
}

// ---------------- last conv (no relu) + fc2/fc3 head (1 px/thread, R5 form) ----------------
__global__ __launch_bounds__(256, 1)
void conv_head_kernel(const float* __restrict__ Fin, const float* __restrict__ P,
                      float* __restrict__ out) {
    const int k = 3;
    __shared__ float4 CW3[1024];
    __shared__ float  CB3[64];
    __shared__ float4 F2W[512];
    __shared__ float  F2B[32];
    __shared__ float4 F3W[80];
    __shared__ float  F3B[12];
    {
        const float4* s1 = (const float4*)(P + OFF_CWT2 + k * 4096);
        for (int i = threadIdx.x; i < 1024; i += 256) CW3[i] = s1[i];
        const float4* s2 = (const float4*)(P + OFF_FC2W2);
        for (int i = threadIdx.x; i < 512; i += 256) F2W[i] = s2[i];
        const float4* s3 = (const float4*)(P + OFF_FC3W4);
        if (threadIdx.x < 80) F3W[threadIdx.x] = s3[threadIdx.x];
        if (threadIdx.x < 64) CB3[threadIdx.x] = P[OFF_CB + k * 64 + threadIdx.x];
        if (threadIdx.x < 32) F2B[threadIdx.x] = P[OFF_FC2B + threadIdx.x];
        if (threadIdx.x < 10) F3B[threadIdx.x] = P[OFF_FC3B + threadIdx.x];
    }
    __syncthreads();

    int n = blockIdx.x * 256 + threadIdx.x;
    int b = n >> 16;
    int pix = n & (NPIX - 1);
    int i = pix >> 8, j = pix & 255;
    float wstr = P[OFF_GW + 2 * k], wdiag = P[OFF_GW + 2 * k + 1];
    float fu = (i > 0) ? wstr : 0.f, fd = (i < 255) ? wstr : 0.f;
    float fl = (j > 0) ? wstr : 0.f, fr = (j < 255) ? wstr : 0.f;
    float ful = (i > 0 && j > 0) ? wdiag : 0.f, fur = (i > 0 && j < 255) ? wdiag : 0.f;
    float fdl = (i < 255 && j > 0) ? wdiag : 0.f, fdr = (i < 255 && j < 255) ? wdiag : 0.f;

    const float* fb = Fin + (size_t)b * WIDTH * NPIX + pix;
    float u[WIDTH];
#pragma unroll
    for (int ch = 0; ch < WIDTH; ch++) {
        const float* yc = fb + (size_t)ch * NPIX;
        float v = yc[0];
        v += fu * yc[-256] + fd * yc[256] + fl * yc[-1] + fr * yc[1];
        v += ful * yc[-257] + fur * yc[-255] + fdl * yc[255] + fdr * yc[257];
        u[ch] = v;
    }

    float f[WIDTH];
#pragma unroll
    for (int co2 = 0; co2 < 32; co2++) {
        float ax = CB3[2 * co2], ay = CB3[2 * co2 + 1];
        const float4* wv = CW3 + co2 * 32;
#pragma unroll
        for (int ci2 = 0; ci2 < 32; ci2++) {
            float4 q = wv[ci2];
            float a0 = u[2 * ci2], a1 = u[2 * ci2 + 1];
            ax += q.x * a0 + q.z * a1;
            ay += q.y * a0 + q.w * a1;
        }
        f[2 * co2] = ax; f[2 * co2 + 1] = ay;
    }

    float2 oo[5];
#pragma unroll
    for (int oc2 = 0; oc2 < 5; oc2++) oo[oc2] = make_float2(F3B[2 * oc2], F3B[2 * oc2 + 1]);
#pragma unroll 1
    for (int m2 = 0; m2 < 16; m2++) {
        float ax = F2B[2 * m2], ay = F2B[2 * m2 + 1];
        const float4* wv = F2W + m2 * 32;
#pragma unroll
        for (int ch2 = 0; ch2 < 32; ch2++) {
            float4 q = wv[ch2];
            float f0 = f[2 * ch2], f1 = f[2 * ch2 + 1];
            ax += q.x * f0 + q.z * f1;
            ay += q.y * f0 + q.w * f1;
        }
        ax = fmaxf(ax, 0.f); ay = fmaxf(ay, 0.f);
#pragma unroll
        for (int oc2 = 0; oc2 < 5; oc2++) {
            float4 q = F3W[oc2 * 16 + m2];
            oo[oc2].x += q.x * ax + q.z * ay;
            oo[oc2].y += q.y * ax + q.w * ay;
        }
    }
    float* ob = out + (size_t)b * OUTC * NPIX + pix;
#pragma unroll
    for (int oc2 = 0; oc2 < 5; oc2++) {
        ob[(size_t)(2 * oc2) * NPIX]     = oo[oc2].x;
        ob[(size_t)(2 * oc2 + 1) * NPIX] = oo[oc2].y;
    }
}

extern "C" void kernel_launch(void* const* d_in, const int* in_sizes, int n_in,
                              void* d_out, int out_size, void* d_ws, size_t ws_size,
                              hipStream_t stream) {
    const float* x     = (const float*)d_in[0];
    const float* eattr = (const float*)d_in[3];
    const float* Wih0  = (const float*)d_in[4];
    const float* Whh0  = (const float*)d_in[5];
    const float* bih0  = (const float*)d_in[6];
    const float* bhh0  = (const float*)d_in[7];
    const float* Wih1  = (const float*)d_in[8];
    const float* Whh1  = (const float*)d_in[9];
    const float* bih1  = (const float*)d_in[10];
    const float* bhh1  = (const float*)d_in[11];
    const float* fc1w  = (const float*)d_in[12];
    const float* fc1b  = (const float*)d_in[13];
    const float* convw = (const float*)d_in[14];
    const float* convb = (const float*)d_in[15];
    const float* gparam= (const float*)d_in[16];
    const float* fc2w  = (const float*)d_in[17];
    const float* fc2b  = (const float*)d_in[18];
    const float* fc3w  = (const float*)d_in[19];
    const float* fc3b  = (const float*)d_in[20];

    float* P  = (float*)d_ws;
    float* FA = P + OFF_FEATS_A;
    float* FB = P + OFF_FEATS_B;

    prep_kernel<<<64, 256, 0, stream>>>(Wih0, Whh0, bih0, bhh0, Wih1, Whh1, bih1, bhh1,
                                        fc1w, fc1b, convw, convb, fc2w, fc2b, fc3w, fc3b,
                                        gparam, eattr, P);
    lstm_fc1_kernel<<<1024, 512, 0, stream>>>(x, P, FA);
    conv_fused_kernel<<<512, 128, 0, stream>>>(FA, FB, P, 0);
    conv_fused_kernel<<<512, 128, 0, stream>>>(FB, FA, P, 1);
    conv_fused_kernel<<<512, 128, 0, stream>>>(FA, FB, P, 2);
    conv_head_kernel<<<512, 256, 0, stream>>>(FB, P, (float*)d_out);
}